// Round 1
// baseline (273.438 us; speedup 1.0000x reference)
//
#include <hip/hip_runtime.h>

// SSIM loss, fused single pass.
// Layout: NCHW (16,3,512,512) fp32 -> 48 contiguous 512x512 planes.
// Per block: 32x32 output tile of one plane.
//   Phase 0: stage clamped inputs into LDS (42 rows x 48 cols, pitch 52).
//   Phase 1: horizontal 11-tap conv of {a, b, a*a, b*b, a*b}; groups of 4
//            consecutive output cols share a 20-float register window
//            (5x ds_read_b128); results stored TRANSPOSED h[q][col][row]
//            with pitch 52 (gcd(52,32)=4 -> uniform 8 words/bank for b128).
//   Phase 2: vertical 11-tap conv, 4 consecutive output rows per thread
//            (4x ds_read_b128 per quantity), SSIM map, block reduce,
//            one float atomicAdd into workspace accumulator.
// Finalize kernel: out = 1 - sum / (16*3*512*512).

#define TS 32          // output tile (rows == cols)
#define HR 42          // staged rows = TS + 10
#define SP 52          // staging pitch in floats (48 cols used)
#define HP 52          // transposed-h pitch in floats (rows 0..41 written, 0..43 read)
#define IMG_H 512
#define IMG_W 512
#define NPLANES 48
#define NPIX (16.0f * 3.0f * 512.0f * 512.0f)

// Gaussian window, sigma=1.5, normalized (computed in double, rounded):
__device__ __constant__ float GW[11] = {
    0.00102838f, 0.00759880f, 0.03600077f, 0.10936070f, 0.21300554f,
    0.26601173f,
    0.21300554f, 0.10936070f, 0.03600077f, 0.00759880f, 0.00102838f
};

__device__ __forceinline__ float clamp01(float x) {
    // fmaxf(NaN, 0) -> 0, so this is nan_to_num(0) + clip(0,1) in one go
    return fminf(fmaxf(x, 0.0f), 1.0f);
}

__global__ __launch_bounds__(256, 3)
void ssim_tile_kernel(const float* __restrict__ imgA,
                      const float* __restrict__ imgB,
                      float* __restrict__ accum) {
    __shared__ float sA[HR * SP];          // 8736 B
    __shared__ float sB[HR * SP];          // 8736 B
    __shared__ float sH[5 * TS * HP];      // 33280 B  (total 50752 B + sRed)
    __shared__ float sRed[4];

    const int t  = threadIdx.x;
    const int cb = blockIdx.x * TS;        // tile col origin in image
    const int rb = blockIdx.y * TS;        // tile row origin in image
    const size_t plane = (size_t)blockIdx.z * (size_t)(IMG_H * IMG_W);
    const float* A = imgA + plane;
    const float* B = imgB + plane;

    // ---------------- Phase 0: stage (zero-padded, clamped) ----------------
    // 42 rows x 12 float4 per image. logical col = cb - 8 + 4u (aligned, W%4==0).
    for (int f = t; f < HR * 12; f += 256) {
        int rr = f / 12;
        int u  = f - rr * 12;
        int ir = rb - 5 + rr;
        int ic = cb - 8 + 4 * u;
        float4 va = make_float4(0.f, 0.f, 0.f, 0.f);
        float4 vb = va;
        if (ir >= 0 && ir < IMG_H && ic >= 0 && ic < IMG_W) {
            va = *(const float4*)(A + ir * IMG_W + ic);
            vb = *(const float4*)(B + ir * IMG_W + ic);
        }
        va.x = clamp01(va.x); va.y = clamp01(va.y);
        va.z = clamp01(va.z); va.w = clamp01(va.w);
        vb.x = clamp01(vb.x); vb.y = clamp01(vb.y);
        vb.z = clamp01(vb.z); vb.w = clamp01(vb.w);
        *(float4*)(sA + rr * SP + 4 * u) = va;
        *(float4*)(sB + rr * SP + 4 * u) = vb;
    }
    __syncthreads();

    // ---------------- Phase 1: horizontal conv, store transposed ----------
    // group = (row rr in 0..41, col-group cg in 0..7); 336 groups.
    // output col c = 4*cg + i; taps use staged phys cols (c+3)..(c+13),
    // register window w[0..19] = phys cols 4*cg .. 4*cg+19 -> index i+j+3.
    for (int gidx = t; gidx < HR * 8; gidx += 256) {
        int rr = gidx % HR;
        int cg = gidx / HR;
        const float* pa = sA + rr * SP + 4 * cg;
        const float* pb = sB + rr * SP + 4 * cg;
        float wa[20], wb[20];
#pragma unroll
        for (int m = 0; m < 5; ++m) {
            *(float4*)(wa + 4 * m) = *(const float4*)(pa + 4 * m);
            *(float4*)(wb + 4 * m) = *(const float4*)(pb + 4 * m);
        }
        float h1[4], h2[4], h11[4], h22[4], h12[4];
#pragma unroll
        for (int i = 0; i < 4; ++i) {
            h1[i] = h2[i] = h11[i] = h22[i] = h12[i] = 0.f;
        }
#pragma unroll
        for (int j = 0; j < 11; ++j) {
            float gj = GW[j];
#pragma unroll
            for (int i = 0; i < 4; ++i) {
                float a  = wa[i + j + 3];
                float b  = wb[i + j + 3];
                float ga = gj * a;
                float gb = gj * b;
                h1[i]  += ga;
                h2[i]  += gb;
                h11[i]  = fmaf(ga, a, h11[i]);
                h22[i]  = fmaf(gb, b, h22[i]);
                h12[i]  = fmaf(ga, b, h12[i]);
            }
        }
        int c0 = cg * 4;
#pragma unroll
        for (int i = 0; i < 4; ++i) {
            int c = c0 + i;
            sH[(0 * TS + c) * HP + rr] = h1[i];
            sH[(1 * TS + c) * HP + rr] = h2[i];
            sH[(2 * TS + c) * HP + rr] = h11[i];
            sH[(3 * TS + c) * HP + rr] = h22[i];
            sH[(4 * TS + c) * HP + rr] = h12[i];
        }
    }
    __syncthreads();

    // ---------------- Phase 2: vertical conv + SSIM + reduce ---------------
    // thread -> (col c, 4 consecutive output rows r0..r0+3).
    // output row r taps h rows r..r+10 -> window w[0..15] = h rows r0..r0+15.
    const int c  = t & 31;
    const int r0 = (t >> 5) * 4;
    float acc[5][4];
#pragma unroll
    for (int q = 0; q < 5; ++q)
#pragma unroll
        for (int i = 0; i < 4; ++i) acc[q][i] = 0.f;

#pragma unroll
    for (int q = 0; q < 5; ++q) {
        const float* ph = sH + (q * TS + c) * HP + r0;
        float w[16];
#pragma unroll
        for (int m = 0; m < 4; ++m)
            *(float4*)(w + 4 * m) = *(const float4*)(ph + 4 * m);
#pragma unroll
        for (int j = 0; j < 11; ++j) {
            float gj = GW[j];
#pragma unroll
            for (int i = 0; i < 4; ++i)
                acc[q][i] = fmaf(gj, w[i + j], acc[q][i]);
        }
    }

    const float C1 = 1.01e-4f;   // 0.01^2 + 1e-6
    const float C2 = 9.01e-4f;   // 0.03^2 + 1e-6
    float lsum = 0.f;
#pragma unroll
    for (int i = 0; i < 4; ++i) {
        float mu1  = acc[0][i], mu2 = acc[1][i];
        float e11  = acc[2][i], e22 = acc[3][i], e12 = acc[4][i];
        float mu1s = mu1 * mu1;
        float mu2s = mu2 * mu2;
        float mu12 = mu1 * mu2;
        float sg1  = fminf(fmaxf(e11 - mu1s, 1e-6f), 1e6f);
        float sg2  = fminf(fmaxf(e22 - mu2s, 1e-6f), 1e6f);
        float sg12 = e12 - mu12;
        float num  = (2.f * mu12 + C1) * (2.f * sg12 + C2);
        float den  = (mu1s + mu2s + C1) * (sg1 + sg2 + C2);
        lsum += num / den;   // den >= C1*C2 > 0, always finite
    }

    // wave64 shuffle reduce, then 4 wave partials via LDS, one atomic/block
#pragma unroll
    for (int off = 32; off > 0; off >>= 1)
        lsum += __shfl_down(lsum, off, 64);
    if ((t & 63) == 0) sRed[t >> 6] = lsum;
    __syncthreads();
    if (t == 0)
        atomicAdd(accum, sRed[0] + sRed[1] + sRed[2] + sRed[3]);
}

__global__ void ssim_finalize_kernel(const float* __restrict__ accum,
                                     float* __restrict__ out) {
    out[0] = 1.0f - accum[0] * (1.0f / NPIX);
}

extern "C" void kernel_launch(void* const* d_in, const int* in_sizes, int n_in,
                              void* d_out, int out_size, void* d_ws, size_t ws_size,
                              hipStream_t stream) {
    const float* img1 = (const float*)d_in[0];
    const float* img2 = (const float*)d_in[1];
    float* out = (float*)d_out;
    float* ws  = (float*)d_ws;

    hipMemsetAsync(ws, 0, sizeof(float), stream);   // ws is re-poisoned each call

    dim3 grid(IMG_W / TS, IMG_H / TS, NPLANES);     // 16 x 16 x 48 = 12288 blocks
    ssim_tile_kernel<<<grid, 256, 0, stream>>>(img1, img2, ws);
    ssim_finalize_kernel<<<1, 1, 0, stream>>>(ws, out);
}

// Round 2
// 205.624 us; speedup vs baseline: 1.3298x; 1.3298x over previous
//
#include <hip/hip_runtime.h>

// SSIM loss — barrier-free streaming separable conv.
// 48 planes of 512x512 fp32. Grid: 4 col-strips x 16 row-strips x 48 planes,
// block = 64 threads = ONE wave (no __syncthreads anywhere).
// Each lane owns 2 adjacent output cols. Per input row (42 steps incl halo):
//   stage row into LDS as interleaved {img1,img2} pairs (double-buffered),
//   read 12 v2f window pairs (even-aligned b64s -> ds_read2_b64),
//   horizontal 11-tap conv of {a,b,a2,b2,ab} via packed-f32 (v_pk_fma_f32),
//   push into an 11-slot REGISTER ring (slot = step mod 11, static via
//   11-step unrolled chunk), then vertical 11-tap conv from ring + SSIM.
// One float atomicAdd per wave; finalize kernel does 1 - sum/N.

typedef float v2f __attribute__((ext_vector_type(2)));

#define IMG    512
#define SCOLS  128          // cols per strip (2 per lane)
#define SROWS  32           // output rows per strip
#define NSTEPS 42           // SROWS + 10 halo rows
#define BUFW   288          // (SCOLS + 16 halo cols) * 2 images, interleaved
#define NPIX   (16.0f * 3.0f * 512.0f * 512.0f)

__device__ __forceinline__ float clamp01(float x) {
    // fmaxf(NaN,0) -> 0: nan_to_num + clip(0,1) in two ops
    return fminf(fmaxf(x, 0.0f), 1.0f);
}

__device__ __forceinline__ float ssim_px(v2f mu, v2f e, float e12, float C1, float C2) {
    v2f musq = mu * mu;                       // {mu1^2, mu2^2}  (pk_mul)
    float mu12 = mu.x * mu.y;
    v2f sig = e - musq;                       // {sig1, sig2}
    v2f lo = {1e-6f, 1e-6f};
    v2f hi = {1e6f, 1e6f};
    sig = __builtin_elementwise_max(sig, lo);
    sig = __builtin_elementwise_min(sig, hi);
    float s12 = e12 - mu12;
    float num = fmaf(2.f, mu12, C1) * fmaf(2.f, s12, C2);
    float den = (musq.x + musq.y + C1) * (sig.x + sig.y + C2);  // >= C1*C2 > 0
    return num * __builtin_amdgcn_rcpf(den);
}

__global__ __launch_bounds__(64, 2)
void ssim_stream_kernel(const float* __restrict__ imgA,
                        const float* __restrict__ imgB,
                        float* __restrict__ accum)
{
    // Gaussian 11-tap, sigma=1.5, normalized (fp64-computed, verified R1)
    constexpr float GW[11] = {
        0.00102838f, 0.00759880f, 0.03600077f, 0.10936070f, 0.21300554f,
        0.26601173f,
        0.21300554f, 0.10936070f, 0.03600077f, 0.00759880f, 0.00102838f
    };
    const float C1 = 1.01e-4f;   // 0.01^2 + 1e-6
    const float C2 = 9.01e-4f;   // 0.03^2 + 1e-6

    __shared__ float sbuf[2][BUFW];   // 2304 B, row double-buffer, interleaved {a,b}

    const int lane = threadIdx.x;
    const int C0 = blockIdx.x * SCOLS;
    const int R0 = blockIdx.y * SROWS;
    const size_t pOff = (size_t)blockIdx.z * (size_t)(IMG * IMG);

    // --- staging task decode (constant per lane) ---
    // 72 float4 tasks per row: t<36 -> imgA quad t ; t>=36 -> imgB quad t-36.
    // LDS word for col xr (= abs col - (C0-8)), img m: 2*xr + m.
    const int t0   = lane;
    const int q0   = (t0 < 36) ? t0 : (t0 - 36);
    const float* sp0 = ((t0 < 36) ? imgA : imgB) + pOff;
    const int col0 = C0 - 8 + 4 * q0;
    const bool okc0 = (col0 >= 0) && (col0 <= IMG - 4);   // quads never straddle edge
    const int wd0  = 8 * q0 + ((t0 < 36) ? 0 : 1);
    const bool has1 = (lane < 8);                          // tasks 64..71: imgB q=28..35
    const int q1   = 28 + lane;
    const int col1 = C0 - 8 + 4 * q1;
    const bool okc1 = (col1 >= 0) && (col1 <= IMG - 4);
    const int wd1  = 8 * q1 + 1;
    const float* sp1 = imgB + pOff;

    // --- register ring: 11 slots x 2 cols x {h1h2 pair, h11h22 pair, h12} ---
    v2f rA[11][2], rB[11][2];
    float rC[11][2];
#pragma unroll
    for (int i = 0; i < 11; ++i) {
        rA[i][0] = 0; rA[i][1] = 0;
        rB[i][0] = 0; rB[i][1] = 0;
        rC[i][0] = 0; rC[i][1] = 0;
    }

    float lsum = 0.f;

    // --- prefetch step 0 ---
    float4 p0 = make_float4(0,0,0,0), p1 = make_float4(0,0,0,0);
    {
        int ir = R0 - 5;
        bool okr = (unsigned)ir < (unsigned)IMG;
        if (okr && okc0) p0 = *(const float4*)(sp0 + (size_t)ir * IMG + col0);
        if (has1 && okr && okc1) p1 = *(const float4*)(sp1 + (size_t)ir * IMG + col1);
    }

#pragma unroll 1
    for (int ch = 0; ch < 4; ++ch) {
#pragma unroll
        for (int u = 0; u < 11; ++u) {
            const int s = ch * 11 + u;          // uniform across wave
            if (s < NSTEPS) {
                const int par = s & 1;

                // 1. stage prefetched row (clamped) -> LDS, interleaved pairs
                {
                    float* d0 = &sbuf[par][wd0];
                    d0[0] = clamp01(p0.x); d0[2] = clamp01(p0.y);
                    d0[4] = clamp01(p0.z); d0[6] = clamp01(p0.w);
                    if (has1) {
                        float* d1 = &sbuf[par][wd1];
                        d1[0] = clamp01(p1.x); d1[2] = clamp01(p1.y);
                        d1[4] = clamp01(p1.z); d1[6] = clamp01(p1.w);
                    }
                }

                // 2. prefetch next row (hides HBM/L2 latency behind this step)
                if (s + 1 < NSTEPS) {
                    int ir = R0 - 5 + s + 1;
                    bool okr = (unsigned)ir < (unsigned)IMG;
                    p0 = make_float4(0,0,0,0);
                    p1 = make_float4(0,0,0,0);
                    if (okr && okc0) p0 = *(const float4*)(sp0 + (size_t)ir * IMG + col0);
                    if (has1 && okr && okc1) p1 = *(const float4*)(sp1 + (size_t)ir * IMG + col1);
                }

                // 3. window read (12 even-aligned v2f) + horizontal conv (packed)
                // lane's output cols: X0 = C0+2c (w[j]), X1 = X0+1 (w[j+1])
                {
                    const v2f* wp = (const v2f*)(&sbuf[par][0]) + (2 * lane + 3);
                    v2f w[12];
#pragma unroll
                    for (int p = 0; p < 12; ++p) w[p] = wp[p];

                    v2f hA0 = 0, hB0 = 0, hA1 = 0, hB1 = 0;
                    float hC0 = 0, hC1 = 0;
#pragma unroll
                    for (int j = 0; j < 11; ++j) {
                        const float gj = GW[j];
                        v2f w0 = w[j], w1 = w[j + 1];
                        v2f g0 = gj * w0;            // {g*a, g*b}   pk_mul
                        v2f g1 = gj * w1;
                        hA0 += g0;                   // {h1, h2}     pk_add
                        hA1 += g1;
                        hB0 += g0 * w0;              // {h11, h22}   pk_fma
                        hB1 += g1 * w1;
                        hC0 = fmaf(g0.x, w0.y, hC0); // h12          fma
                        hC1 = fmaf(g1.x, w1.y, hC1);
                    }
                    rA[u][0] = hA0; rA[u][1] = hA1;
                    rB[u][0] = hB0; rB[u][1] = hB1;
                    rC[u][0] = hC0; rC[u][1] = hC1;
                }

                // 4. vertical conv from ring + SSIM (out row R0+s-10)
                if (s >= 10) {
                    v2f vA0 = 0, vB0 = 0, vA1 = 0, vB1 = 0;
                    float vC0 = 0, vC1 = 0;
#pragma unroll
                    for (int i = 0; i < 11; ++i) {
                        const int sl = (u + 1 + i) % 11;   // slot of step s-10+i (static)
                        const float gi = GW[i];
                        vA0 += gi * rA[sl][0]; vA1 += gi * rA[sl][1];
                        vB0 += gi * rB[sl][0]; vB1 += gi * rB[sl][1];
                        vC0 = fmaf(gi, rC[sl][0], vC0);
                        vC1 = fmaf(gi, rC[sl][1], vC1);
                    }
                    lsum += ssim_px(vA0, vB0, vC0, C1, C2);
                    lsum += ssim_px(vA1, vB1, vC1, C1, C2);
                }
            }
        }
    }

    // wave64 reduce, one atomic per wave
#pragma unroll
    for (int off = 32; off >= 1; off >>= 1)
        lsum += __shfl_down(lsum, off, 64);
    if (lane == 0) atomicAdd(accum, lsum);
}

__global__ void ssim_finalize_kernel(const float* __restrict__ accum,
                                     float* __restrict__ out) {
    out[0] = 1.0f - accum[0] * (1.0f / NPIX);
}

extern "C" void kernel_launch(void* const* d_in, const int* in_sizes, int n_in,
                              void* d_out, int out_size, void* d_ws, size_t ws_size,
                              hipStream_t stream) {
    const float* img1 = (const float*)d_in[0];
    const float* img2 = (const float*)d_in[1];
    float* out = (float*)d_out;
    float* ws  = (float*)d_ws;

    hipMemsetAsync(ws, 0, sizeof(float), stream);   // ws re-poisoned every call

    dim3 grid(IMG / SCOLS, IMG / SROWS, 48);        // 4 x 16 x 48 = 3072 waves
    ssim_stream_kernel<<<grid, 64, 0, stream>>>(img1, img2, ws);
    ssim_finalize_kernel<<<1, 1, 0, stream>>>(ws, out);
}